// Round 1
// 414.639 us; speedup vs baseline: 1.0100x; 1.0100x over previous
//
#include <hip/hip_runtime.h>

// ---------------------------------------------------------------------------
// PGN step, fused. All tensors fp32 in HBM; bf16 MFMA internally.
// B=2, N=512, F=MID=OUT=128, Z=256.
//
// out[b,j] = relu( h1[b,j] + (msg1[b,j] + msgg[b] + be +
//                  max_{i: adj[b,i,j]>0}( msg2[b,i] + E[b,i,j,:]@We )) @ Wo2 + bo2 )
// ---------------------------------------------------------------------------

typedef __bf16 bf16x8 __attribute__((ext_vector_type(8)));
typedef float  f32x4  __attribute__((ext_vector_type(4)));

#define MFMA16(a,b,c) __builtin_amdgcn_mfma_f32_16x16x32_bf16(a,b,c,0,0,0)

union BFrag { bf16x8 v; unsigned short s[8]; unsigned u[4]; };

__device__ __forceinline__ unsigned packbf(float lo, float hi){ // 2xf32 -> 2xbf16 trunc
  return __builtin_amdgcn_perm(__builtin_bit_cast(unsigned, hi),
                               __builtin_bit_cast(unsigned, lo), 0x07060302u);
}
__device__ __forceinline__ unsigned short f2bt(float f){
  return (unsigned short)(__builtin_bit_cast(unsigned, f) >> 16);
}
__device__ __forceinline__ unsigned short f2b(float f){    // RNE
  unsigned u = __builtin_bit_cast(unsigned, f);
  u = u + 0x7FFFu + ((u >> 16) & 1u);
  return (unsigned short)(u >> 16);
}
__device__ __forceinline__ float b2f(unsigned short u){
  unsigned v = ((unsigned)u) << 16;
  return __builtin_bit_cast(float, v);
}

#define WAITVM(N) asm volatile("s_waitcnt vmcnt(" #N ")" ::: "memory")

// workspace layout (float elements)
#define WS_MS2  0            // msg_2  (B*N*128) f32
#define WS_MS1  131072       // msg_1  (B*N*128) f32
#define WS_H1   262144       // h_1    (B*N*128) f32
#define WS_MSGG 393216       // msg_g  (B*128) f32
#define WS_PART 393472       // partial maxes, bf16: [b][jt:32][s:32][16][128]
#define WS_WEFR 4587776      // We frags: 32*64*8 bf16

// ---------------------------------------------------------------------------
// K1: msg_1 / msg_2 / h_1 (1024x256x128 GEMMs). Now nt-split 4-ways:
//   768 blocks = 3 mats x 64 row-tiles x 4 nt-pairs, 1 wave each -> 3 waves/CU
//   (was 192 single-wave blocks, <1 wave/CU, latency-exposed on W loads).
// msg_g (blocks 768,769), We frag pre-pack (block 770).
// MFMA frag conventions (m89-verified):
//   A: lane holds A[m=lane&15][k=(lane>>4)*8+j]
//   B: lane holds B[k=(lane>>4)*8+j][n=lane&15]
//   D: lane reg r holds D[row=(lane>>4)*4+r][col=lane&15]
// ---------------------------------------------------------------------------
__global__ __launch_bounds__(64) void k1_small(
    const float* __restrict__ node,
    const float* __restrict__ hidden,
    const float* __restrict__ graph,
    const float* __restrict__ W1, const float* __restrict__ b1,
    const float* __restrict__ W2, const float* __restrict__ b2,
    const float* __restrict__ Wo1,const float* __restrict__ bo1,
    const float* __restrict__ Wg, const float* __restrict__ bg,
    const float* __restrict__ We,
    float* __restrict__ ws)
{
  int bid  = blockIdx.x;
  int lane = threadIdx.x;
  int col = lane & 15, quad = lane >> 4;

  if (bid < 768) {
    int mat = bid >> 8;              // 0: W1->msg1, 1: W2->msg2, 2: Wo1->h1
    int rt  = (bid >> 2) & 63;       // row tile
    int np  = bid & 3;               // nt pair: handles nt = np*2, np*2+1
    int r0  = rt * 16;               // flat row b*512+n
    const float* W  = (mat==0) ? W1 : (mat==1) ? W2 : Wo1;
    const float* bb = (mat==0) ? b1 : (mat==1) ? b2 : bo1;
    float* dst = ws + ((mat==0) ? WS_MS1 : (mat==1) ? WS_MS2 : WS_H1);

    bf16x8 a[8];
    long rowb = (long)(r0 + col) * 128;
#pragma unroll
    for (int kk = 0; kk < 8; ++kk) {
      const float* src = (kk < 4) ? node : hidden;
      int f = (kk & 3) * 32 + quad * 8;
      f32x4 v0 = *(const f32x4*)(src + rowb + f);
      f32x4 v1 = *(const f32x4*)(src + rowb + f + 4);
      BFrag t;
      t.u[0] = packbf(v0[0], v0[1]); t.u[1] = packbf(v0[2], v0[3]);
      t.u[2] = packbf(v1[0], v1[1]); t.u[3] = packbf(v1[2], v1[3]);
      a[kk] = t.v;
    }
    f32x4 acc[2];
#pragma unroll
    for (int t = 0; t < 2; ++t) acc[t] = (f32x4)0.f;
#pragma unroll
    for (int kk = 0; kk < 8; ++kk) {
      BFrag bf[2];
#pragma unroll
      for (int t = 0; t < 2; ++t) {
        int nt = np*2 + t;
#pragma unroll
        for (int j = 0; j < 8; ++j)
          bf[t].s[j] = f2bt(W[(kk*32 + quad*8 + j)*128 + nt*16 + col]);
      }
#pragma unroll
      for (int t = 0; t < 2; ++t) acc[t] = MFMA16(a[kk], bf[t].v, acc[t]);
    }
#pragma unroll
    for (int t = 0; t < 2; ++t) {
      int nt = np*2 + t;
      float bv = bb[nt*16 + col];
#pragma unroll
      for (int r = 0; r < 4; ++r) {
        int row = r0 + quad*4 + r;
        dst[(long)row*128 + nt*16 + col] = acc[t][r] + bv;
      }
    }
  } else if (bid < 770) {
    // msg_g[b] = graph_fts[b] @ Wg + bg
    int b = bid - 768;
    float a0 = 0.f, a1 = 0.f;
    for (int k = 0; k < 128; ++k) {
      float g = graph[b*128 + k];
      a0 += g * Wg[k*128 + lane];
      a1 += g * Wg[k*128 + 64 + lane];
    }
    ws[WS_MSGG + b*128 + lane]      = a0 + bg[lane];
    ws[WS_MSGG + b*128 + 64 + lane] = a1 + bg[64 + lane];
  } else {
    // pre-pack We into per-lane MFMA B-frag layout (bf16, RNE) for K2
    unsigned short* wf = (unsigned short*)(ws + WS_WEFR);
#pragma unroll
    for (int kk = 0; kk < 4; ++kk)
#pragma unroll
      for (int nt = 0; nt < 8; ++nt) {
        BFrag t;
#pragma unroll
        for (int e = 0; e < 8; ++e)
          t.s[e] = f2b(We[(kk*32 + quad*8 + e)*128 + nt*16 + col]);
        *(bf16x8*)(wf + ((kk*8 + nt)*64 + lane)*8) = t.v;
      }
  }
}

// ---------------------------------------------------------------------------
// K2: hot loop, DMA-pipelined. 1 wave/block; block = (b, jt: 16 j's, s: 16 i's).
// Per i, the 8 KB slice E[b,i,j0:j0+16,:] is DMA'd to LDS via global_load_lds
// dwordx4, XOR-swizzled on the GLOBAL side (LDS chunk j*32+(g^j) holds global
// chunk (j,g)) so frag ds_read_b128 at col*512B + ((cb)^col)*16B is spread
// across 8 bank-quads (optimal 8-phase).  Depth-3 slot pipeline, vmcnt(16)
// per iter -> 2 slices in flight/wave; LDS 28.5 KB -> 5 blocks/CU ->
// 80 KB/CU in flight >> Little's-law need (~9 KB at 900cy HBM latency).
// msg2 staged bf16, TRANSPOSED [i][col][nt] so per-iter read is one b128.
// ---------------------------------------------------------------------------
__device__ __forceinline__ void issue_slice(const float* ei, void* lbase, int lane){
  int l5 = lane >> 5, s5 = lane & 31;
#pragma unroll
  for (int inst = 0; inst < 8; ++inst) {
    int j = inst*2 + l5;
    const float* gp = ei + j*128 + ((s5 ^ j) << 2);
    __builtin_amdgcn_global_load_lds(
        (const __attribute__((address_space(1))) void*)gp,
        (__attribute__((address_space(3))) void*)((char*)lbase + inst*1024),
        16, 0, 0);
  }
}

__global__ __launch_bounds__(64, 1) void k2_main(
    const float* __restrict__ E,
    const float* __restrict__ adj,
    const float* __restrict__ msg2,
    const unsigned short* __restrict__ wefrag,
    unsigned short* __restrict__ part)
{
  __shared__ alignas(16) unsigned char lds_raw[3*8192 + 4096 + 512];
  unsigned short* const m2l  = (unsigned short*)(lds_raw + 24576);
  unsigned short* const adjl = (unsigned short*)(lds_raw + 24576 + 4096);

  const int bid = blockIdx.x;
  const int jt = bid & 31, s = (bid >> 5) & 31, b = bid >> 10;
  const int lane = threadIdx.x;
  const int col = lane & 15, quad = lane >> 4;
  const int i0 = s * 16, j0 = jt * 16;

  const float* Eb = E + ((long)(b*512 + i0)*512 + j0) * 128;  // +i*65536 floats

  // ---- resident We B-frags (coalesced 16B loads of K1's pre-pack)
  bf16x8 bfr[4][8];
#pragma unroll
  for (int kk = 0; kk < 4; ++kk)
#pragma unroll
    for (int nt = 0; nt < 8; ++nt)
      bfr[kk][nt] = *(const bf16x8*)(wefrag + ((kk*8 + nt)*64 + lane)*8);

  // ---- stage msg2 slice (16 x 128) bf16, transposed [i][col(16)][nt(8)]
#pragma unroll
  for (int p = 0; p < 8; ++p) {
    int f = p*256 + lane*4;
    int i = f >> 7, c = f & 127;
    int cc = c & 15, nt = c >> 4;
    const float* mp = msg2 + (long)(b*512 + i0 + i)*128 + c;
    f32x4 v = *(const f32x4*)mp;
#pragma unroll
    for (int e = 0; e < 4; ++e)
      m2l[i*128 + (cc + e)*8 + nt] = f2b(v[e]);
  }
  // ---- stage adj slice (16 x 16) as bf16 (0/1 exact)
  {
    int row = lane >> 2, c4 = (lane & 3) * 4;
    f32x4 v = *(const f32x4*)(adj + (long)(b*512 + i0 + row)*512 + j0 + c4);
    uint2 uu;
    uu.x = (unsigned)f2bt(v[0]) | ((unsigned)f2bt(v[1]) << 16);
    uu.y = (unsigned)f2bt(v[2]) | ((unsigned)f2bt(v[3]) << 16);
    *(uint2*)(adjl + row*16 + c4) = uu;
  }
  __syncthreads();

  // ---- prime DMA pipeline: slices 0..2 into slots 0..2
#pragma unroll
  for (int d = 0; d < 3; ++d)
    issue_slice(Eb + (long)d*65536, lds_raw + d*8192, lane);

  f32x4 mx[8];
#pragma unroll
  for (int nt = 0; nt < 8; ++nt) mx[nt] = (f32x4)(-1.0e6f);

  auto body = [&](int ii, int slot) {
    const float* sl = (const float*)(lds_raw + slot * 8192);
    BFrag a[4];
#pragma unroll
    for (int kk = 0; kk < 4; ++kk) {
      int cb = kk*8 + quad*2;
      f32x4 v0 = *(const f32x4*)(sl + col*128 + ((cb    ) ^ col)*4);
      f32x4 v1 = *(const f32x4*)(sl + col*128 + ((cb + 1) ^ col)*4);
      a[kk].u[0] = packbf(v0[0], v0[1]); a[kk].u[1] = packbf(v0[2], v0[3]);
      a[kk].u[2] = packbf(v1[0], v1[1]); a[kk].u[3] = packbf(v1[2], v1[3]);
    }
    BFrag m2f;
    m2f.v = *(const bf16x8*)(m2l + ii*128 + col*8);   // one b128, quad-broadcast
    ushort4 av = *(const ushort4*)(adjl + ii*16 + quad*4);
    f32x4 biasv;
    biasv[0] = b2f(av.x)*1.0e6f - 1.0e6f;
    biasv[1] = b2f(av.y)*1.0e6f - 1.0e6f;
    biasv[2] = b2f(av.z)*1.0e6f - 1.0e6f;
    biasv[3] = b2f(av.w)*1.0e6f - 1.0e6f;
    f32x4 T[8];
#pragma unroll
    for (int nt = 0; nt < 8; ++nt) T[nt] = biasv + b2f(m2f.s[nt]);
#pragma unroll
    for (int kk = 0; kk < 4; ++kk)
#pragma unroll
      for (int nt = 0; nt < 8; ++nt)
        T[nt] = MFMA16(a[kk].v, bfr[kk][nt], T[nt]);
#pragma unroll
    for (int nt = 0; nt < 8; ++nt)
#pragma unroll
      for (int r = 0; r < 4; ++r)
        mx[nt][r] = fmaxf(mx[nt][r], T[nt][r]);
  };

  int slot = 0;
#pragma unroll 1
  for (int ii = 0; ii < 13; ++ii) {
    WAITVM(16);                 // drain slice ii; ii+1, ii+2 stay in flight
    body(ii, slot);
    asm volatile("" ::: "memory");
    issue_slice(Eb + (long)(ii+3)*65536, lds_raw + slot*8192, lane);
    slot = (slot == 2) ? 0 : slot + 1;
  }
  WAITVM(16); body(13, 1);
  WAITVM(8);  body(14, 2);
  WAITVM(0);  body(15, 0);

  // ---- store partial max tile [16 j][128 n] as bf16
  unsigned short* pp = part + ((long)((b*32 + jt)*32 + s)) * 2048;
#pragma unroll
  for (int nt = 0; nt < 8; ++nt)
#pragma unroll
    for (int r = 0; r < 4; ++r)
      pp[(quad*4 + r)*128 + nt*16 + col] = f2b(mx[nt][r]);
}

// ---------------------------------------------------------------------------
// K3: combine 32 bf16 partials -> + msg1 + msgg + be -> bf16 -> @Wo2 (MFMA)
//     -> + h1 + bo2 -> relu -> fp32 out.
// Now 64 blocks x 4 waves: each wave reduces 8 of the 32 s-slices, LDS
// combine (lane-contiguous layout, conflict-free), then each wave does the
// MFMA + epilogue for 2 of the 8 nt tiles.  (Was 64 single-wave blocks =
// 64 waves on the whole GPU, serially chewing 128 cross-XCD loads/lane.)
// ---------------------------------------------------------------------------
__global__ __launch_bounds__(256) void k3_out(
    const float* __restrict__ ws,
    const float* __restrict__ Wo2,
    const float* __restrict__ be,
    const float* __restrict__ bo2,
    float* __restrict__ out)
{
  __shared__ float lred[4][8][4][64];   // [kk][e][wave][lane], 32 KB

  int bid = blockIdx.x;
  int b = bid >> 5, jt = bid & 31, j0 = jt * 16;
  int tid = threadIdx.x;
  int wave = tid >> 6, lane = tid & 63, col = lane & 15, quad = lane >> 4;

  const unsigned short* part =
      (const unsigned short*)(ws + WS_PART) + ((long)((b*32 + jt)*32))*2048;
  const float* msg1 = ws + WS_MS1;
  const float* msgg = ws + WS_MSGG + b*128;
  const float* h1   = ws + WS_H1;

  // ---- each wave reduces its 8 s-slices
  float v[4][8];
#pragma unroll
  for (int kk = 0; kk < 4; ++kk)
#pragma unroll
    for (int e = 0; e < 8; ++e) v[kk][e] = -1.0e6f;
#pragma unroll
  for (int kk = 0; kk < 4; ++kk) {
    int off = kk*32 + quad*8;
    const unsigned short* p0 = part + col*128 + off + (long)wave*8*2048;
#pragma unroll
    for (int s8 = 0; s8 < 8; ++s8) {
      BFrag t; t.v = *(const bf16x8*)(p0 + s8*2048);
#pragma unroll
      for (int e = 0; e < 8; ++e) v[kk][e] = fmaxf(v[kk][e], b2f(t.s[e]));
    }
  }
#pragma unroll
  for (int kk = 0; kk < 4; ++kk)
#pragma unroll
    for (int e = 0; e < 8; ++e) lred[kk][e][wave][lane] = v[kk][e];
  __syncthreads();

  // ---- combine 4 waves' partials + msg1 + msgg + be -> A-frags (all waves)
  BFrag af[4];
#pragma unroll
  for (int kk = 0; kk < 4; ++kk) {
    int off = kk*32 + quad*8;
    float vv[8];
#pragma unroll
    for (int e = 0; e < 8; ++e) {
      float m = fmaxf(lred[kk][e][0][lane], lred[kk][e][1][lane]);
      m = fmaxf(m, lred[kk][e][2][lane]);
      vv[e] = fmaxf(m, lred[kk][e][3][lane]);
    }
    const float* m1 = msg1 + (long)(b*512 + j0 + col)*128 + off;
    f32x4 w0 = *(const f32x4*)m1, w1 = *(const f32x4*)(m1 + 4);
#pragma unroll
    for (int r = 0; r < 4; ++r) {
      float g0 = msgg[off + r]     + be[off + r];
      float g1 = msgg[off + 4 + r] + be[off + 4 + r];
      af[kk].s[r]     = f2b(vv[r]     + w0[r] + g0);
      af[kk].s[4 + r] = f2b(vv[4 + r] + w1[r] + g1);
    }
  }

  // ---- each wave: MFMA + epilogue for nt = wave*2, wave*2+1
  f32x4 acc[2];
#pragma unroll
  for (int t = 0; t < 2; ++t) acc[t] = (f32x4)0.f;
#pragma unroll
  for (int kk = 0; kk < 4; ++kk) {
    BFrag bf[2];
#pragma unroll
    for (int t = 0; t < 2; ++t) {
      int nt = wave*2 + t;
#pragma unroll
      for (int j = 0; j < 8; ++j)
        bf[t].s[j] = f2bt(Wo2[(kk*32 + quad*8 + j)*128 + nt*16 + col]);
    }
#pragma unroll
    for (int t = 0; t < 2; ++t) acc[t] = MFMA16(af[kk].v, bf[t].v, acc[t]);
  }

#pragma unroll
  for (int t = 0; t < 2; ++t) {
    int nt = wave*2 + t;
    float bv = bo2[nt*16 + col];
#pragma unroll
    for (int r = 0; r < 4; ++r) {
      int row = j0 + quad*4 + r;
      long idx = (long)(b*512 + row)*128 + nt*16 + col;
      float vo = h1[idx] + acc[t][r] + bv;
      out[idx] = vo < 0.f ? 0.f : vo;
    }
  }
}

// ---------------------------------------------------------------------------
extern "C" void kernel_launch(void* const* d_in, const int* in_sizes, int n_in,
                              void* d_out, int out_size, void* d_ws, size_t ws_size,
                              hipStream_t stream)
{
  const float* node   = (const float*)d_in[0];
  const float* E      = (const float*)d_in[1];
  const float* graph  = (const float*)d_in[2];
  const float* adj    = (const float*)d_in[3];
  const float* hidden = (const float*)d_in[4];
  const float* W1  = (const float*)d_in[5];
  const float* b1  = (const float*)d_in[6];
  const float* W2  = (const float*)d_in[7];
  const float* b2  = (const float*)d_in[8];
  const float* We  = (const float*)d_in[9];
  const float* be  = (const float*)d_in[10];
  const float* Wg  = (const float*)d_in[11];
  const float* bg  = (const float*)d_in[12];
  const float* Wo1 = (const float*)d_in[13];
  const float* bo1 = (const float*)d_in[14];
  const float* Wo2 = (const float*)d_in[15];
  const float* bo2 = (const float*)d_in[16];
  float* ws  = (float*)d_ws;
  float* out = (float*)d_out;

  hipLaunchKernelGGL(k1_small, dim3(771), dim3(64), 0, stream,
                     node, hidden, graph, W1, b1, W2, b2, Wo1, bo1, Wg, bg, We, ws);
  hipLaunchKernelGGL(k2_main, dim3(2048), dim3(64), 0, stream,
                     E, adj, ws + WS_MS2, (const unsigned short*)(ws + WS_WEFR),
                     (unsigned short*)(ws + WS_PART));
  hipLaunchKernelGGL(k3_out, dim3(64), dim3(256), 0, stream,
                     ws, Wo2, be, bo2, out);
}